// Round 3
// baseline (568.474 us; speedup 1.0000x reference)
//
#include <hip/hip_runtime.h>
#include <math.h>

// Problem constants (fixed by the reference)
#define BGRAPH 1024
#define NNODE  16384
#define KP1    164     // ceil(0.01*16384)
#define KP2    17      // ceil(0.1*164)
#define KP3    2       // ceil(0.1*17)
#define TPB    256

typedef unsigned int uint;

// float -> order-preserving uint (larger float => larger uint)
__device__ __forceinline__ uint sortable(float s) {
    uint u = __float_as_uint(s);
    return (u & 0x80000000u) ? ~u : (u | 0x80000000u);
}
__device__ __forceinline__ float unsortable(uint k) {
    uint u = (k & 0x80000000u) ? (k & 0x7FFFFFFFu) : ~k;
    return __uint_as_float(u);
}

// Bitonic sort of 256 (key,idx) pairs in LDS, 256 threads.
// Final order: key descending; ties: idx ascending (matches jax.lax.top_k).
__device__ __forceinline__ void bitonic256(uint* k, uint* i) {
    const int t = threadIdx.x;
    for (int sz = 2; sz <= 256; sz <<= 1) {
        for (int st = sz >> 1; st > 0; st >>= 1) {
            __syncthreads();
            int p = t ^ st;
            if (p > t) {
                uint ka = k[t], kb = k[p];
                uint ia = i[t], ib = i[p];
                bool before = (ka > kb) || (ka == kb && ia < ib); // a precedes b
                bool up = ((t & sz) == 0);
                if (up ? !before : before) {
                    k[t] = kb; k[p] = ka;
                    i[t] = ib; i[p] = ia;
                }
            }
        }
    }
    __syncthreads();
}

extern "C" __global__ __launch_bounds__(TPB, 3)
void net_topk_fused(const float* __restrict__ x,
                    const float* __restrict__ wp1,
                    const float* __restrict__ W1,
                    const float* __restrict__ b1,
                    const float* __restrict__ wp2,
                    const float* __restrict__ wp3,
                    const float* __restrict__ W2,
                    const float* __restrict__ b2,
                    float* __restrict__ out)
{
    __shared__ uint  hist[256];
    __shared__ uint  ckey[256];
    __shared__ uint  cidx[256];
    __shared__ float xsel[KP1 * 5];
    __shared__ float h1[KP1 * 65];     // stride 65: conflict-free column access
    __shared__ float s2v[KP2];
    __shared__ uint  s2row[KP2];
    __shared__ float s3v[KP3];
    __shared__ uint  s3pos[KP3];
    __shared__ uint  sh_b, sh_hi, sh_nc;

    const int tid = threadIdx.x;
    const int g   = blockIdx.x;

    // pool1 weights (uniform -> scalar regs)
    const float w0 = wp1[0], w1 = wp1[1], w2 = wp1[2], w3 = wp1[3], w4 = wp1[4];
    float nq = w0 * w0;
    nq = fmaf(w1, w1, nq); nq = fmaf(w2, w2, nq);
    nq = fmaf(w3, w3, nq); nq = fmaf(w4, w4, nq);
    const float nrm1 = sqrtf(nq);

    // ---- Phase 1: scores for 16384 nodes; keys in registers ----
    uint key[64];
    const float4* xb = reinterpret_cast<const float4*>(x + (size_t)g * NNODE * 5);
    #pragma unroll
    for (int it = 0; it < 16; ++it) {
        const int G = tid + it * 256;               // group of 4 nodes
        const float4* p = xb + (size_t)G * 5;       // 80 bytes, 16B aligned
        float4 A = p[0], B = p[1], C = p[2], D = p[3], E = p[4];
        float z;
        z = A.x * w0; z = fmaf(A.y, w1, z); z = fmaf(A.z, w2, z); z = fmaf(A.w, w3, z); z = fmaf(B.x, w4, z);
        key[it * 4 + 0] = sortable(tanhf(z / nrm1));
        z = B.y * w0; z = fmaf(B.z, w1, z); z = fmaf(B.w, w2, z); z = fmaf(C.x, w3, z); z = fmaf(C.y, w4, z);
        key[it * 4 + 1] = sortable(tanhf(z / nrm1));
        z = C.z * w0; z = fmaf(C.w, w1, z); z = fmaf(D.x, w2, z); z = fmaf(D.y, w3, z); z = fmaf(D.z, w4, z);
        key[it * 4 + 2] = sortable(tanhf(z / nrm1));
        z = D.w * w0; z = fmaf(E.x, w1, z); z = fmaf(E.y, w2, z); z = fmaf(E.z, w3, z); z = fmaf(E.w, w4, z);
        key[it * 4 + 3] = sortable(tanhf(z / nrm1));
    }

    // ---- Phase 2: radix-select the 164th largest key (4 passes of 8 bits) ----
    uint Krem = KP1;
    uint prefix = 0;
    #pragma unroll
    for (int pass = 0; pass < 4; ++pass) {
        const int pshift = 32 - 8 * pass;   // only used when pass>0 (compile-time)
        const int bshift = 24 - 8 * pass;
        __syncthreads();
        hist[tid] = 0;
        __syncthreads();
        #pragma unroll
        for (int j = 0; j < 64; ++j) {
            uint k = key[j];
            bool match = (pass == 0) || ((k >> (pshift & 31)) == prefix);
            if (match) atomicAdd(&hist[(k >> bshift) & 255u], 1u);
        }
        __syncthreads();
        // suffix sum: hist[t] = count of keys (matching prefix) with byte >= t
        for (int off = 1; off < 256; off <<= 1) {
            uint v = hist[tid];
            uint w = (tid + off < 256) ? hist[tid + off] : 0u;
            __syncthreads();
            hist[tid] = v + w;
            __syncthreads();
        }
        uint Sb  = hist[tid];
        uint Sb1 = (tid < 255) ? hist[tid + 1] : 0u;
        if (Sb >= Krem && Sb1 < Krem) { sh_b = (uint)tid; sh_hi = Sb1; }
        __syncthreads();
        prefix = (prefix << 8) | sh_b;
        Krem  -= sh_hi;                     // still need Krem of keys == current prefix
    }
    // prefix == threshold key T; take all keys > T, plus Krem of == T (lowest idx)

    // ---- Phase 3: collect candidates >= T, sort, keep first 164 ----
    if (tid == 0) sh_nc = 0;
    __syncthreads();
    #pragma unroll
    for (int j = 0; j < 64; ++j) {
        uint k = key[j];
        if (k >= prefix) {
            uint pos = atomicAdd(&sh_nc, 1u);
            if (pos < 256u) {
                ckey[pos] = k;
                cidx[pos] = 4u * (uint)tid + (uint)((j >> 2) * 1024) + (uint)(j & 3);
            }
        }
    }
    __syncthreads();
    uint nc = sh_nc; if (nc > 256u) nc = 256u;
    if ((uint)tid >= nc) { ckey[tid] = 0u; cidx[tid] = 0x7FFFFFFFu; }
    bitonic256(ckey, cidx);
    // slots 0..163: selected nodes in output order (score desc, idx asc)

    // ---- Phase 4: gather + gate ----
    if (tid < KP1) {
        float s = unsortable(ckey[tid]);
        const float* xr = x + ((size_t)g * NNODE + cidx[tid]) * 5;
        #pragma unroll
        for (int f = 0; f < 5; ++f) xsel[tid * 5 + f] = xr[f] * s;
    }
    __syncthreads();

    // ---- Phase 5: nn1  h1[i][c] = b1[c] + sum_f xsel[i][f]*W1[c][f] ----
    for (int t = tid; t < KP1 * 64; t += TPB) {   // 10496 = 41*256 exactly
        int i = t >> 6, c = t & 63;
        float acc = b1[c];
        #pragma unroll
        for (int f = 0; f < 5; ++f) acc = fmaf(xsel[i * 5 + f], W1[c * 5 + f], acc);
        h1[i * 65 + c] = acc;
    }
    __syncthreads();

    // ---- Phase 6: pool2 (top 17 of 164) ----
    {
        if (tid < KP1) {
            float nw = 0.f, acc = 0.f;
            for (int f = 0; f < 64; ++f) nw = fmaf(wp2[f], wp2[f], nw);
            for (int f = 0; f < 64; ++f) acc = fmaf(h1[tid * 65 + f], wp2[f], acc);
            float s = tanhf(acc / sqrtf(nw));
            ckey[tid] = sortable(s); cidx[tid] = (uint)tid;
        } else {
            ckey[tid] = 0u; cidx[tid] = 0x7FFFFFFFu;
        }
    }
    bitonic256(ckey, cidx);
    if (tid < KP2) { s2v[tid] = unsortable(ckey[tid]); s2row[tid] = cidx[tid]; }
    __syncthreads();

    // ---- Phase 7: pool3 (top 2 of 17); h2 = h1[row]*s2 ----
    {
        if (tid < KP2) {
            float s2 = s2v[tid];
            uint row = s2row[tid];
            float nw = 0.f, acc = 0.f;
            for (int f = 0; f < 64; ++f) nw = fmaf(wp3[f], wp3[f], nw);
            for (int f = 0; f < 64; ++f) acc = fmaf(h1[row * 65 + f] * s2, wp3[f], acc);
            float s = tanhf(acc / sqrtf(nw));
            ckey[tid] = sortable(s); cidx[tid] = (uint)tid;
        } else {
            ckey[tid] = 0u; cidx[tid] = 0x7FFFFFFFu;
        }
    }
    bitonic256(ckey, cidx);
    if (tid < KP3) { s3v[tid] = unsortable(ckey[tid]); s3pos[tid] = cidx[tid]; }
    __syncthreads();

    // ---- Phase 8: nn2 + store (2 rows x 3 outs per graph) ----
    if (tid < KP3 * 3) {
        int r = tid / 3, o = tid % 3;
        uint p2  = s3pos[r];
        uint row = s2row[p2];
        float s2 = s2v[p2], s3 = s3v[r];
        float acc = b2[o];
        for (int f = 0; f < 64; ++f) {
            float hf = (h1[row * 65 + f] * s2) * s3;   // faithful to ref rounding order
            acc = fmaf(hf, W2[o * 64 + f], acc);
        }
        out[((size_t)g * KP3 + r) * 3 + o] = acc;
    }
}

extern "C" void kernel_launch(void* const* d_in, const int* in_sizes, int n_in,
                              void* d_out, int out_size, void* d_ws, size_t ws_size,
                              hipStream_t stream) {
    // setup_inputs order:
    // 0:x 1:edge_index(unused) 2:batch(unused) 3:w_pool1 4:W1 5:b1 6:w_pool2 7:w_pool3 8:W2 9:b2
    const float* x   = (const float*)d_in[0];
    const float* wp1 = (const float*)d_in[3];
    const float* W1  = (const float*)d_in[4];
    const float* b1  = (const float*)d_in[5];
    const float* wp2 = (const float*)d_in[6];
    const float* wp3 = (const float*)d_in[7];
    const float* W2  = (const float*)d_in[8];
    const float* b2  = (const float*)d_in[9];
    float* out = (float*)d_out;

    hipLaunchKernelGGL(net_topk_fused, dim3(BGRAPH), dim3(TPB), 0, stream,
                       x, wp1, W1, b1, wp2, wp3, W2, b2, out);
}

// Round 4
// 549.763 us; speedup vs baseline: 1.0340x; 1.0340x over previous
//
#include <hip/hip_runtime.h>
#include <math.h>

// Problem constants (fixed by the reference)
#define BGRAPH 1024
#define NNODE  16384
#define KP1    164     // ceil(0.01*16384)
#define KP2    17      // ceil(0.1*164)
#define KP3    2       // ceil(0.1*17)
#define KSEL   256     // pool1 selection margin (>= KP1 + tie slack; tie runs are ~1-2 elems)
#define TPB    256

typedef unsigned int uint;

// float -> order-preserving uint (larger float => larger uint)
__device__ __forceinline__ uint sortable(float s) {
    uint u = __float_as_uint(s);
    return (u & 0x80000000u) ? ~u : (u | 0x80000000u);
}
__device__ __forceinline__ float unsortable(uint k) {
    uint u = (k & 0x80000000u) ? (k & 0x7FFFFFFFu) : ~k;
    return __uint_as_float(u);
}

// Bitonic sort of 256 (key,idx) pairs in LDS, 256 threads.
// Final order: key descending; ties: idx ascending (matches jax.lax.top_k / np ref).
__device__ __forceinline__ void bitonic256(uint* k, uint* i) {
    const int t = threadIdx.x;
    for (int sz = 2; sz <= 256; sz <<= 1) {
        for (int st = sz >> 1; st > 0; st >>= 1) {
            __syncthreads();
            int p = t ^ st;
            if (p > t) {
                uint ka = k[t], kb = k[p];
                uint ia = i[t], ib = i[p];
                bool before = (ka > kb) || (ka == kb && ia < ib); // a precedes b
                bool up = ((t & sz) == 0);
                if (up ? !before : before) {
                    k[t] = kb; k[p] = ka;
                    i[t] = ib; i[p] = ia;
                }
            }
        }
    }
    __syncthreads();
}

extern "C" __global__ __launch_bounds__(TPB, 4)
void net_topk_fused(const float* __restrict__ x,
                    const float* __restrict__ wp1,
                    const float* __restrict__ W1,
                    const float* __restrict__ b1,
                    const float* __restrict__ wp2,
                    const float* __restrict__ wp3,
                    const float* __restrict__ W2,
                    const float* __restrict__ b2,
                    float* __restrict__ out)
{
    __shared__ uint  hist[256];
    __shared__ uint  ckey[256];
    __shared__ uint  cidx[256];
    __shared__ float xsel[KP1 * 5];    // gated x rows of the 164 selected nodes
    __shared__ float h17[KP2 * 65];    // raw h1 rows of the 17 pool2 winners (stride 65)
    __shared__ float s2v[KP2];
    __shared__ uint  s2row[KP2];
    __shared__ float s3v[KP3];
    __shared__ uint  s3pos[KP3];
    __shared__ uint  sh_b, sh_hi, sh_nc;

    const int tid = threadIdx.x;
    const int g   = blockIdx.x;

    // pool1 weights (uniform -> scalar regs)
    const float w0 = wp1[0], w1 = wp1[1], w2 = wp1[2], w3 = wp1[3], w4 = wp1[4];
    float nq = w0 * w0;
    nq = fmaf(w1, w1, nq); nq = fmaf(w2, w2, nq);
    nq = fmaf(w3, w3, nq); nq = fmaf(w4, w4, nq);
    const float nrm1 = sqrtf(nq);

    // ---- Phase 1: z = x.w for 16384 nodes (NO tanh here: tanh is monotone,
    //      so z-order == score-order up to float ties, handled by KSEL margin) ----
    uint key[64];
    const float4* xb = reinterpret_cast<const float4*>(x + (size_t)g * NNODE * 5);
    #pragma unroll
    for (int it = 0; it < 16; ++it) {
        const int G = tid + it * 256;               // group of 4 nodes
        const float4* p = xb + (size_t)G * 5;       // 80 bytes, 16B aligned
        float4 A = p[0], B = p[1], C = p[2], D = p[3], E = p[4];
        float z;
        z = A.x * w0; z = fmaf(A.y, w1, z); z = fmaf(A.z, w2, z); z = fmaf(A.w, w3, z); z = fmaf(B.x, w4, z);
        key[it * 4 + 0] = sortable(z);
        z = B.y * w0; z = fmaf(B.z, w1, z); z = fmaf(B.w, w2, z); z = fmaf(C.x, w3, z); z = fmaf(C.y, w4, z);
        key[it * 4 + 1] = sortable(z);
        z = C.z * w0; z = fmaf(C.w, w1, z); z = fmaf(D.x, w2, z); z = fmaf(D.y, w3, z); z = fmaf(D.z, w4, z);
        key[it * 4 + 2] = sortable(z);
        z = D.w * w0; z = fmaf(E.x, w1, z); z = fmaf(E.y, w2, z); z = fmaf(E.z, w3, z); z = fmaf(E.w, w4, z);
        key[it * 4 + 3] = sortable(z);
    }

    // ---- Phase 2: radix-select the KSEL-th largest z-key (4 passes of 8 bits) ----
    uint Krem = KSEL;
    uint prefix = 0;
    #pragma unroll
    for (int pass = 0; pass < 4; ++pass) {
        const int pshift = 32 - 8 * pass;   // only used when pass>0
        const int bshift = 24 - 8 * pass;
        __syncthreads();
        hist[tid] = 0;
        __syncthreads();
        #pragma unroll
        for (int j = 0; j < 64; ++j) {
            uint k = key[j];
            bool match = (pass == 0) || ((k >> (pshift & 31)) == prefix);
            if (match) atomicAdd(&hist[(k >> bshift) & 255u], 1u);
        }
        __syncthreads();
        // suffix sum: hist[t] = count of keys (matching prefix) with byte >= t
        for (int off = 1; off < 256; off <<= 1) {
            uint v = hist[tid];
            uint w = (tid + off < 256) ? hist[tid + off] : 0u;
            __syncthreads();
            hist[tid] = v + w;
            __syncthreads();
        }
        uint Sb  = hist[tid];
        uint Sb1 = (tid < 255) ? hist[tid + 1] : 0u;
        if (Sb >= Krem && Sb1 < Krem) { sh_b = (uint)tid; sh_hi = Sb1; }
        __syncthreads();
        prefix = (prefix << 8) | sh_b;
        Krem  -= sh_hi;
    }
    // prefix == threshold key T (z-rank KSEL); #(>T) < 256, #(>=T) >= 256

    // ---- Phase 3: collect 256 candidates with z-key >= T ----
    if (tid == 0) sh_nc = 0;
    __syncthreads();
    #pragma unroll
    for (int j = 0; j < 64; ++j) {
        uint k = key[j];
        if (k >= prefix) {
            uint pos = atomicAdd(&sh_nc, 1u);
            if (pos < 256u) {
                ckey[pos] = k;
                cidx[pos] = 4u * (uint)tid + (uint)((j >> 2) * 1024) + (uint)(j & 3);
            }
        }
    }
    __syncthreads();

    // ---- Phase 3b: exact scores (tanh(z/||w||)) for candidates only, then
    //      sort by (tanh desc, idx asc) — reproduces ref tie semantics exactly ----
    {
        uint nc = sh_nc; if (nc > 256u) nc = 256u;   // always 256 by construction
        if ((uint)tid < nc) {
            float z = unsortable(ckey[tid]);
            ckey[tid] = sortable(tanhf(z / nrm1));   // same rounding path as ref
        } else { ckey[tid] = 0u; cidx[tid] = 0x7FFFFFFFu; }
    }
    bitonic256(ckey, cidx);
    // slots 0..163: selected nodes in ref output order

    // ---- Phase 4: gather + gate (keep own row in regs for phase 5/6) ----
    float xr0 = 0.f, xr1 = 0.f, xr2 = 0.f, xr3 = 0.f, xr4 = 0.f;
    if (tid < KP1) {
        float s = unsortable(ckey[tid]);
        const float* xr = x + ((size_t)g * NNODE + cidx[tid]) * 5;
        xr0 = xr[0] * s; xr1 = xr[1] * s; xr2 = xr[2] * s; xr3 = xr[3] * s; xr4 = xr[4] * s;
        xsel[tid * 5 + 0] = xr0; xsel[tid * 5 + 1] = xr1; xsel[tid * 5 + 2] = xr2;
        xsel[tid * 5 + 3] = xr3; xsel[tid * 5 + 4] = xr4;
    }
    __syncthreads();

    // ---- Phase 5+6 fused: pool2 score per row, h1 computed on the fly
    //      (identical fma chain/order as materialized version -> bit-identical) ----
    {
        float nw = 0.f;
        for (int f = 0; f < 64; ++f) nw = fmaf(wp2[f], wp2[f], nw);
        if (tid < KP1) {
            float acc = 0.f;
            for (int c = 0; c < 64; ++c) {
                float h = b1[c];
                h = fmaf(xr0, W1[c * 5 + 0], h);
                h = fmaf(xr1, W1[c * 5 + 1], h);
                h = fmaf(xr2, W1[c * 5 + 2], h);
                h = fmaf(xr3, W1[c * 5 + 3], h);
                h = fmaf(xr4, W1[c * 5 + 4], h);
                acc = fmaf(h, wp2[c], acc);
            }
            float s = tanhf(acc / sqrtf(nw));
            ckey[tid] = sortable(s); cidx[tid] = (uint)tid;
        } else {
            ckey[tid] = 0u; cidx[tid] = 0x7FFFFFFFu;
        }
    }
    bitonic256(ckey, cidx);
    if (tid < KP2) { s2v[tid] = unsortable(ckey[tid]); s2row[tid] = cidx[tid]; }
    __syncthreads();

    // ---- Phase 6b: materialize raw h1 rows for the 17 winners only ----
    for (int t = tid; t < KP2 * 64; t += TPB) {
        int j = t >> 6, c = t & 63;
        int row = (int)s2row[j];
        float h = b1[c];
        #pragma unroll
        for (int f = 0; f < 5; ++f) h = fmaf(xsel[row * 5 + f], W1[c * 5 + f], h);
        h17[j * 65 + c] = h;
    }
    __syncthreads();

    // ---- Phase 7: pool3 (top 2 of 17) on gated rows h1*s2 ----
    {
        float nw = 0.f;
        for (int f = 0; f < 64; ++f) nw = fmaf(wp3[f], wp3[f], nw);
        if (tid < KP2) {
            float s2 = s2v[tid];
            float acc = 0.f;
            for (int c = 0; c < 64; ++c) acc = fmaf(h17[tid * 65 + c] * s2, wp3[c], acc);
            float s = tanhf(acc / sqrtf(nw));
            ckey[tid] = sortable(s); cidx[tid] = (uint)tid;
        } else {
            ckey[tid] = 0u; cidx[tid] = 0x7FFFFFFFu;
        }
    }
    bitonic256(ckey, cidx);
    if (tid < KP3) { s3v[tid] = unsortable(ckey[tid]); s3pos[tid] = cidx[tid]; }
    __syncthreads();

    // ---- Phase 8: nn2 + store (2 rows x 3 outs per graph) ----
    if (tid < KP3 * 3) {
        int r = tid / 3, o = tid % 3;
        uint p2 = s3pos[r];
        float s2 = s2v[p2], s3 = s3v[r];
        float acc = b2[o];
        for (int c = 0; c < 64; ++c) {
            float hf = (h17[p2 * 65 + c] * s2) * s3;   // faithful to ref rounding order
            acc = fmaf(hf, W2[o * 64 + c], acc);
        }
        out[((size_t)g * KP3 + r) * 3 + o] = acc;
    }
}

extern "C" void kernel_launch(void* const* d_in, const int* in_sizes, int n_in,
                              void* d_out, int out_size, void* d_ws, size_t ws_size,
                              hipStream_t stream) {
    // setup_inputs order:
    // 0:x 1:edge_index(unused) 2:batch(unused) 3:w_pool1 4:W1 5:b1 6:w_pool2 7:w_pool3 8:W2 9:b2
    const float* x   = (const float*)d_in[0];
    const float* wp1 = (const float*)d_in[3];
    const float* W1  = (const float*)d_in[4];
    const float* b1  = (const float*)d_in[5];
    const float* wp2 = (const float*)d_in[6];
    const float* wp3 = (const float*)d_in[7];
    const float* W2  = (const float*)d_in[8];
    const float* b2  = (const float*)d_in[9];
    float* out = (float*)d_out;

    hipLaunchKernelGGL(net_topk_fused, dim3(BGRAPH), dim3(TPB), 0, stream,
                       x, wp1, W1, b1, wp2, wp3, W2, b2, out);
}